// Round 5
// baseline (291.419 us; speedup 1.0000x reference)
//
#include <hip/hip_runtime.h>
#include <hip/hip_bf16.h>

// QuantizedLinearINT4: out = x @ dequant(W).T + bias
// M=8192, N=OUT=4096, K=IN=4096.
// Round-5: register-level fragment read-ahead. Each phase issues the 12
// ds_read_b128 for the NEXT phase's fragments (set P/Q double-buffer), then
// runs 32 MFMA on fragments read last phase -> LDS reads hide under MFMA.
// Sync per phase: vmcnt(4) -> barrier -> stage 4 gload_lds -> 12 ds_read -> MFMA.
// (vmcnt before barrier: each wave drains its own staging loads before any
// wave reads cross-wave-staged LDS.)

typedef __bf16 bf16;
typedef __attribute__((ext_vector_type(8))) __bf16 bf16x8;
typedef __attribute__((ext_vector_type(4))) float f32x4;
typedef __attribute__((ext_vector_type(4))) unsigned int u32x4;

#define OUT_DIM 4096
#define IN_DIM  4096
#define M_DIM   8192

// ---------- Pass 1: dequant int4 -> bf16 W[OUT][IN] ----------
__global__ __launch_bounds__(256) void dequant_w_kernel(
    const int* __restrict__ wp, const float* __restrict__ scale,
    const float* __restrict__ zp, bf16* __restrict__ W)
{
  const int t = blockIdx.x * 256 + threadIdx.x;
  const long j = (long)t * 8;
  const int o = (int)(j >> 12);
  const float s = scale[o];
  const float zs = zp[o] * s;
  const int4 p = *(const int4*)(wp + (long)t * 4);
  const int v[4] = {p.x, p.y, p.z, p.w};
  union { bf16 h[8]; u32x4 u; } r;
#pragma unroll
  for (int q = 0; q < 4; ++q) {
    r.h[2*q]   = (bf16)((float)(v[q] & 15) * s - zs);
    r.h[2*q+1] = (bf16)((float)((v[q] >> 4) & 15) * s - zs);
  }
  *(u32x4*)(W + j) = r.u;
}

// ---------- Pass 2: cast x f32 -> bf16 ----------
__global__ __launch_bounds__(256) void cvt_x_kernel(
    const float* __restrict__ x, bf16* __restrict__ xb)
{
  const long t = (long)blockIdx.x * 256 + threadIdx.x;
  const long i = t * 8;
  const f32x4 a = *(const f32x4*)(x + i);
  const f32x4 b = *(const f32x4*)(x + i + 4);
  union { bf16 h[8]; u32x4 u; } r;
#pragma unroll
  for (int q = 0; q < 4; ++q) { r.h[q] = (bf16)a[q]; r.h[4+q] = (bf16)b[q]; }
  *(u32x4*)(xb + i) = r.u;
}

// ---------- Pass 3: 256x256 pipelined GEMM-BT with fused bias ----------
// 512 threads = 8 waves (2M x 4N), per-wave output 128x64, acc[8][4] f32x4.
// LDS sm[2buf][4 halves][256][32] bf16, st_16x32 swizzle; linear gload_lds
// dest + pre-swizzled global source + swizzled ds_read address.
// Schedule (phase = half K-tile, 2 phases/K-tile):
//   alpha(T): vmcnt -> barrier -> stage S(T+1,A1B1) -> read R(T,1)->Q -> MFMA(T,0) on P
//   beta(T):  vmcnt -> barrier -> stage S(T+2,A0B0) -> read R(T+1,0)->P -> MFMA(T,1) on Q
// Staging leads reads by 2 phases; 8 loads in flight, vmcnt(4) drains oldest 4.
__global__ __launch_bounds__(512, 2) void gemm_bt_bias_kernel(
    const bf16* __restrict__ A, const bf16* __restrict__ B,
    const float* __restrict__ bias, float* __restrict__ C)
{
  const int N = OUT_DIM, K = IN_DIM;
  const int NT = IN_DIM / 64;            // 64 K-tiles

  __shared__ bf16 sm[2][4][256][32];     // 128 KiB

  // T1: XCD-aware bijective swizzle (512 blocks, 512 % 8 == 0)
  const int bid = blockIdx.x;
  const int swz = (bid & 7) * (512 / 8) + (bid >> 3);
  const int bm = swz >> 4;               // 32 row-tiles
  const int bn = swz & 15;               // 16 col-tiles

  const int tid  = threadIdx.x;
  const int wave = tid >> 6;
  const int lane = tid & 63;
  const int wr = wave >> 2;              // 0..1 -> 128-row strip
  const int wc = wave & 3;               // 0..3 -> 64-col strip

  const long row0 = (long)bm * 256;
  const long col0 = (long)bn * 256;

  // --- staging source addresses (pre-swizzled: linear LDS dest, swizzled global src) ---
  const int L0 = tid * 16;
  const int L1 = 8192 + tid * 16;
  const int Lw0 = L0 ^ (((L0 >> 9) & 1) << 5);
  const int Lw1 = L1 ^ (((L1 >> 9) & 1) << 5);
  const int sr0 = Lw0 >> 6, sc0 = (Lw0 & 63) >> 1;   // row, bf16-col within [256][32] half
  const int sr1 = Lw1 >> 6, sc1 = (Lw1 & 63) >> 1;
  const bf16* a0 = A + (row0 + sr0) * (long)K + sc0;
  const bf16* a1 = A + (row0 + sr1) * (long)K + sc1;
  const bf16* b0 = B + (col0 + sr0) * (long)K + sc0;
  const bf16* b1 = B + (col0 + sr1) * (long)K + sc1;

#define STAGE(P0, P1, HALF, KOFF) do {                                          \
    __builtin_amdgcn_global_load_lds(                                           \
        (const __attribute__((address_space(1))) void*)((P0) + (KOFF)),         \
        (__attribute__((address_space(3))) void*)((char*)(HALF) + L0), 16, 0, 0);\
    __builtin_amdgcn_global_load_lds(                                           \
        (const __attribute__((address_space(1))) void*)((P1) + (KOFF)),         \
        (__attribute__((address_space(3))) void*)((char*)(HALF) + L1), 16, 0, 0);\
  } while (0)

  // --- ds_read per-lane constants (swizzle folds to ^((lane&8)<<2)) ---
  const int lane15 = lane & 15;
  const int rb = (lane15 * 64 + ((lane >> 4) << 4)) ^ ((lane & 8) << 2);
  const int wrB = wr * 8192;             // byte offset of wave's 128-row strip in A half
  const int wcB = wc * 4096;             // byte offset of wave's 64-row strip in B half

  f32x4 acc[8][4] = {};
  bf16x8 pa[8], pb[4];                   // fragment set P
  bf16x8 qa[8], qb[4];                   // fragment set Q

#define RD(RA, RB, BUF, KS) do {                                                \
    const char* Ab = (const char*)&sm[BUF][KS][0][0];                           \
    const char* Bb = (const char*)&sm[BUF][2 + (KS)][0][0];                     \
    _Pragma("unroll")                                                           \
    for (int f = 0; f < 4; ++f) RB[f] = *(const bf16x8*)(Bb + wcB + f*1024 + rb); \
    _Pragma("unroll")                                                           \
    for (int f = 0; f < 8; ++f) RA[f] = *(const bf16x8*)(Ab + wrB + f*1024 + rb); \
  } while (0)

#define MFMAS(CA, CB) do {                                                      \
    __builtin_amdgcn_s_setprio(1);                                              \
    _Pragma("unroll")                                                           \
    for (int i = 0; i < 8; ++i)                                                 \
      _Pragma("unroll")                                                         \
      for (int j = 0; j < 4; ++j)                                               \
        acc[i][j] = __builtin_amdgcn_mfma_f32_16x16x32_bf16(CA[i], CB[j], acc[i][j], 0, 0, 0); \
    __builtin_amdgcn_s_setprio(0);                                              \
  } while (0)

  // Prologue: stage S(0,A0B0), S(0,A1B1); drain S(0,A0B0); stage S(1,A0B0); read R(0,0)->P
  STAGE(a0, a1, &sm[0][0][0][0], 0);
  STAGE(b0, b1, &sm[0][2][0][0], 0);
  STAGE(a0, a1, &sm[0][1][0][0], 32);
  STAGE(b0, b1, &sm[0][3][0][0], 32);
  asm volatile("s_waitcnt vmcnt(4)" ::: "memory");
  __builtin_amdgcn_s_barrier();
  STAGE(a0, a1, &sm[1][0][0][0], 64);
  STAGE(b0, b1, &sm[1][2][0][0], 64);
  RD(pa, pb, 0, 0);

  for (int T = 0; T < NT; ++T) {
    const int buf = T & 1;
    const int nbuf = buf ^ 1;
    const bool st1 = (T + 1 < NT);
    const bool st2 = (T + 2 < NT);

    // alpha(T): drain S(T,A1B1); stage S(T+1,A1B1); read R(T,1)->Q; MFMA(T,0) on P
    if (st1) asm volatile("s_waitcnt vmcnt(4)" ::: "memory");
    else     asm volatile("s_waitcnt vmcnt(0)" ::: "memory");
    __builtin_amdgcn_s_barrier();
    if (st1) {
      STAGE(a0, a1, &sm[nbuf][1][0][0], (T + 1) * 64 + 32);
      STAGE(b0, b1, &sm[nbuf][3][0][0], (T + 1) * 64 + 32);
    }
    RD(qa, qb, buf, 1);
    MFMAS(pa, pb);

    // beta(T): drain S(T+1,A0B0); stage S(T+2,A0B0); read R(T+1,0)->P; MFMA(T,1) on Q
    if (st1) asm volatile("s_waitcnt vmcnt(4)" ::: "memory");
    else     asm volatile("s_waitcnt vmcnt(0)" ::: "memory");
    __builtin_amdgcn_s_barrier();
    if (st2) {
      STAGE(a0, a1, &sm[buf][0][0][0], (T + 2) * 64);
      STAGE(b0, b1, &sm[buf][2][0][0], (T + 2) * 64);
    }
    if (st1) RD(pa, pb, nbuf, 0);
    MFMAS(qa, qb);
  }

  // Epilogue: C/D layout col=lane&15, row=(lane>>4)*4+reg; fused bias.
  const long cr0 = row0 + wr * 128 + ((lane >> 4) << 2);
  const long cc0 = col0 + wc * 64 + lane15;
#pragma unroll
  for (int j = 0; j < 4; ++j) {
    const long gc = cc0 + j * 16;
    const float bv = bias[gc];
#pragma unroll
    for (int mf = 0; mf < 8; ++mf) {
      float* cp = C + (cr0 + mf * 16) * (long)N + gc;
#pragma unroll
      for (int r = 0; r < 4; ++r)
        cp[(long)r * N] = acc[mf][j][r] + bv;
    }
  }
#undef RD
#undef MFMAS
#undef STAGE
}

extern "C" void kernel_launch(void* const* d_in, const int* in_sizes, int n_in,
                              void* d_out, int out_size, void* d_ws, size_t ws_size,
                              hipStream_t stream)
{
  const float* x     = (const float*)d_in[0];
  const int*   wp    = (const int*)d_in[1];
  const float* scale = (const float*)d_in[2];
  const float* zp    = (const float*)d_in[3];
  const float* bias  = (const float*)d_in[4];
  float* out = (float*)d_out;

  bf16* Wb = (bf16*)d_ws;
  bf16* Xb = (bf16*)((char*)d_ws + (size_t)OUT_DIM * IN_DIM * 2);

  dequant_w_kernel<<<(OUT_DIM * (long)IN_DIM / 8) / 256, 256, 0, stream>>>(wp, scale, zp, Wb);
  cvt_x_kernel<<<(M_DIM * (long)IN_DIM / 8) / 256, 256, 0, stream>>>(x, Xb);
  // grid = (8192/256)*(4096/256) = 32*16 = 512 blocks, 512 threads
  gemm_bt_bias_kernel<<<512, 512, 0, stream>>>(Xb, Wb, bias, out);
}